// Round 5
// baseline (360.698 us; speedup 1.0000x reference)
//
#include <hip/hip_runtime.h>
#include <math.h>

#define E_TOTAL 100000
#define N_TILES 6250   // E_TOTAL / 16

typedef __attribute__((ext_vector_type(4))) float f32x4;

// fc2F[col][k] = fc_w2[k][col] * 0.25f (fp32), col in [0,2304), k in [0,16).
__global__ void prep_fc2_kernel(const float* __restrict__ fw2,
                                float* __restrict__ fc2F) {
  int tid = blockIdx.x * 256 + threadIdx.x;   // 144*256 = 36864 exactly
  int col = tid >> 4;
  int k   = tid & 15;
  fc2F[col * 16 + k] = fw2[k * 2304 + col] * 0.25f;   // fc_w2 / sqrt(HID=16)
}

// __launch_bounds__(256, 4): LDS (38.4 KB) caps residency at 4 blocks/CU anyway;
// telling the allocator raises the VGPR budget 84 -> 128 so the 12 hoisted
// weight loads can stay in flight instead of serializing into 4 batches.
__global__ __launch_bounds__(256, 4) void tp_kernel(
    const float* __restrict__ feature,   // (20000, 80)
    const int*   __restrict__ edge,      // (2, 100000)
    const float* __restrict__ elem,      // (100000, 10)
    const float* __restrict__ esh,       // (100000, 4)
    const float* __restrict__ fw1,       // (10, 16)
    const float* __restrict__ fc2F,      // (2304, 16) fp32, pre-scaled
    float* __restrict__ out,             // (100000, 80)
    float silu_c)
{
  __shared__ __align__(16) float fc1s[160];            // fc_w1 / sqrt(10)
  __shared__ __align__(16) float s1T[4][32][20];       // [u][edge]
  __shared__ __align__(16) float v1T[4][16][3][20];    // [u][i][edge]
  __shared__ __align__(16) float dT[4][16][16];        // [u][edge] : v1.v2
  __shared__ __align__(16) float s2A[4][16];
  __shared__ __align__(16) float v2A[4][3][16];
  __shared__ __align__(16) float elemL[4][160];        // [edge*10 + j]
  __shared__ __align__(16) float hF[4][16][16];        // [edge][k] fp32
  __shared__ int dstA[4][16];

  const int tid    = threadIdx.x;
  const int wid    = tid >> 6;
  const int l      = tid & 63;
  const int lane16 = l & 15;
  const int quad   = l >> 4;
  const int quad4  = quad * 4;

  int tile = blockIdx.x * 4 + wid;
  if (tile >= N_TILES) tile = N_TILES - 1;   // duplicate tile: identical writes
  const int eg0 = tile * 16;

  // ---- stage tiny per-tile inputs (all coalesced) ----
  if (tid < 160) fc1s[tid] = fw1[tid] / sqrtf(10.0f);
  if (l < 16) dstA[wid][l] = edge[E_TOTAL + eg0 + l];     // edge[1] row
  elemL[wid][l] = elem[eg0 * 10 + l];
  elemL[wid][64 + l] = elem[eg0 * 10 + 64 + l];
  if (l < 32) elemL[wid][128 + l] = elem[eg0 * 10 + 128 + l];
  {
    float v = esh[eg0 * 4 + l];
    int e = l >> 2, c = l & 3;
    if (c == 0) s2A[wid][e] = v;
    else        v2A[wid][c - 1][e] = v;
  }
  __syncthreads();

  // ---- feature gather: lane = channel c, loop over 16 edges ----
  {
    const int c0 = l;
    const int u0 = (c0 - 32) / 3, i0 = (c0 - 32) % 3;   // used only when c0 >= 32
    #pragma unroll 4
    for (int e = 0; e < 16; ++e) {
      int base = dstA[wid][e] * 80;
      float v = feature[base + c0];
      if (c0 < 32) s1T[wid][c0][e] = v;
      else         v1T[wid][u0][i0][e] = v;
    }
    if (l < 16) {
      const int c1 = 64 + l;
      const int u1 = (c1 - 32) / 3, i1 = (c1 - 32) % 3;
      for (int e = 0; e < 16; ++e) {
        int base = dstA[wid][e] * 80;
        v1T[wid][u1][i1][e] = feature[base + c1];
      }
    }
  }
  __syncthreads();

  // ---- h = SILU_C * silu(elem @ fc1) fp32 ; dT[u][e] = v1[u,:].v2 ----
  {
    const int e = lane16;
    #pragma unroll
    for (int q = 0; q < 4; ++q) {
      int k = quad + 4 * q;
      float a = 0.f;
      #pragma unroll
      for (int j = 0; j < 10; ++j)
        a = fmaf(elemL[wid][e * 10 + j], fc1s[j * 16 + k], a);
      hF[wid][e][k] = silu_c * a / (1.f + __expf(-a));
    }
    #pragma unroll
    for (int q = 0; q < 4; ++q) {
      int u = quad + 4 * q;
      dT[wid][u][e] = v1T[wid][u][0][e] * v2A[wid][0][e]
                    + v1T[wid][u][1][e] * v2A[wid][1][e]
                    + v1T[wid][u][2][e] * v2A[wid][2][e];
    }
  }
  __syncthreads();

  // ---- load h rows for this lane's 4 edges into registers (fp32) ----
  float hr[4][16];
  #pragma unroll
  for (int r = 0; r < 4; ++r) {
    #pragma unroll
    for (int k = 0; k < 16; ++k)
      hr[r][k] = hF[wid][quad4 + r][k];
  }

  const f32x4 zero4 = {0.f, 0.f, 0.f, 0.f};
  f32x4 as0a = zero4, as0b = zero4, at1 = zero4, as3a = zero4, as3b = zero4;
  f32x4 at2a = zero4, at2b = zero4, at2c = zero4;

  // W0 (cols u*32 + {0,16} + lane16) and W1 (cols 1024 + u*16 + lane16), u in [0,32)
  // All 12 dwordx4 weight loads hoisted; with the 128-VGPR budget they can
  // now remain in flight (compiler emits counted vmcnt for in-order use).
  #pragma unroll 1
  for (int u = 0; u < 32; ++u) {
    const float* B0 = fc2F + (u * 32 + lane16) * 16;
    const float* B1 = B0 + 256;                           // +16 cols
    const float* B2 = fc2F + (1024 + u * 16 + lane16) * 16;
    f32x4 x0[4], x1[4], x2[4];
    #pragma unroll
    for (int kk = 0; kk < 4; ++kk) {
      x0[kk] = *(const f32x4*)(B0 + 4 * kk);
      x1[kk] = *(const f32x4*)(B1 + 4 * kk);
      x2[kk] = *(const f32x4*)(B2 + 4 * kk);
    }
    f32x4 d0 = zero4, d1 = zero4, d2 = zero4;
    #pragma unroll
    for (int kk = 0; kk < 4; ++kk) {
      #pragma unroll
      for (int j = 0; j < 4; ++j) {
        const int k = kk * 4 + j;
        #pragma unroll
        for (int r = 0; r < 4; ++r) {
          d0[r] = fmaf(hr[r][k], x0[kk][j], d0[r]);
          d1[r] = fmaf(hr[r][k], x1[kk][j], d1[r]);
          d2[r] = fmaf(hr[r][k], x2[kk][j], d2[r]);
        }
      }
    }
    f32x4 s1v = *(const f32x4*)&s1T[wid][u][quad4];
    as0a += d0 * s1v;   // d[r] = w[edge=quad4+r][col], col = lane16 (+16)
    as0b += d1 * s1v;
    at1  += d2 * s1v;
  }

  // W2 (cols 1536 + u*16) and W3 (cols 1792 + u*32 + {0,16}), u in [0,16)
  #pragma unroll 1
  for (int u = 0; u < 16; ++u) {
    const float* B2a = fc2F + (1536 + u * 16 + lane16) * 16;
    const float* B3a = fc2F + (1792 + u * 32 + lane16) * 16;
    const float* B3b = B3a + 256;                         // +16 cols
    f32x4 y0[4], y1[4], y2[4];
    #pragma unroll
    for (int kk = 0; kk < 4; ++kk) {
      y0[kk] = *(const f32x4*)(B2a + 4 * kk);
      y1[kk] = *(const f32x4*)(B3a + 4 * kk);
      y2[kk] = *(const f32x4*)(B3b + 4 * kk);
    }
    f32x4 dw2 = zero4, d3a = zero4, d3b = zero4;
    #pragma unroll
    for (int kk = 0; kk < 4; ++kk) {
      #pragma unroll
      for (int j = 0; j < 4; ++j) {
        const int k = kk * 4 + j;
        #pragma unroll
        for (int r = 0; r < 4; ++r) {
          dw2[r] = fmaf(hr[r][k], y0[kk][j], dw2[r]);
          d3a[r] = fmaf(hr[r][k], y1[kk][j], d3a[r]);
          d3b[r] = fmaf(hr[r][k], y2[kk][j], d3b[r]);
        }
      }
    }
    f32x4 v1v0 = *(const f32x4*)&v1T[wid][u][0][quad4];
    f32x4 v1v1 = *(const f32x4*)&v1T[wid][u][1][quad4];
    f32x4 v1v2 = *(const f32x4*)&v1T[wid][u][2][quad4];
    at2a += dw2 * v1v0;
    at2b += dw2 * v1v1;
    at2c += dw2 * v1v2;
    f32x4 dv = *(const f32x4*)&dT[wid][u][quad4];
    as3a += d3a * dv;
    as3b += d3b * dv;
  }

  // ---- epilogue: out_s = C0*s2*acc0 + C3*acc3 ; out_v = C1*v2*t1 + C2*s2*t2 ----
  f32x4 s2v = *(const f32x4*)&s2A[wid][quad4];
  f32x4 v20 = *(const f32x4*)&v2A[wid][0][quad4];
  f32x4 v21 = *(const f32x4*)&v2A[wid][1][quad4];
  f32x4 v22 = *(const f32x4*)&v2A[wid][2][quad4];
  const float CC = 0.14433756729740643f;  // 1/sqrt(48) = C0 = C1 = C2; C3 = 0.25
  #pragma unroll
  for (int r = 0; r < 4; ++r) {
    int e = eg0 + quad4 + r;
    float* op = out + (size_t)e * 80;
    op[lane16]      = CC * s2v[r] * as0a[r] + 0.25f * as3a[r];
    op[16 + lane16] = CC * s2v[r] * as0b[r] + 0.25f * as3b[r];
    float t1r = at1[r];
    float* vp = op + 32 + lane16 * 3;
    vp[0] = CC * (v20[r] * t1r + s2v[r] * at2a[r]);
    vp[1] = CC * (v21[r] * t1r + s2v[r] * at2b[r]);
    vp[2] = CC * (v22[r] * t1r + s2v[r] * at2c[r]);
  }
}

extern "C" void kernel_launch(void* const* d_in, const int* in_sizes, int n_in,
                              void* d_out, int out_size, void* d_ws, size_t ws_size,
                              hipStream_t stream) {
  const float* feature = (const float*)d_in[0];
  const int*   edge    = (const int*)d_in[1];
  const float* elem    = (const float*)d_in[2];
  const float* esh     = (const float*)d_in[3];
  const float* fw1     = (const float*)d_in[4];
  const float* fw2     = (const float*)d_in[5];
  float* out = (float*)d_out;
  float* fc2F = (float*)d_ws;   // 2304*16*4 B = 147456 B

  // SILU_C: replicate np.trapz(silu(x)^2 * N(0,1) pdf, 200001 pts on [-12,12])
  const int NPTS = 200001;
  const double dx = 24.0 / 200000.0;
  const double inv_sqrt2pi = 0.3989422804014326779;
  double sum = 0.0;
  double x0 = -12.0;
  double s0 = x0 / (1.0 + exp(-x0));
  double y0 = s0 * s0 * exp(-0.5 * x0 * x0) * inv_sqrt2pi;
  for (int i = 1; i < NPTS; ++i) {
    double x1 = -12.0 + i * dx;
    double s1 = x1 / (1.0 + exp(-x1));
    double y1 = s1 * s1 * exp(-0.5 * x1 * x1) * inv_sqrt2pi;
    sum += 0.5 * (y0 + y1) * dx;
    y0 = y1;
  }
  float silu_c = (float)(1.0 / sqrt(sum));

  hipLaunchKernelGGL(prep_fc2_kernel, dim3(144), dim3(256), 0, stream, fw2, fc2F);
  hipLaunchKernelGGL(tp_kernel, dim3(1563), dim3(256), 0, stream,
                     feature, edge, elem, esh, fw1, fc2F, out, silu_c);
}

// Round 6
// 206.202 us; speedup vs baseline: 1.7492x; 1.7492x over previous
//
#include <hip/hip_runtime.h>
#include <math.h>

#define E_TOTAL 100000
#define N_TILES 6250   // E_TOTAL / 16

typedef __attribute__((ext_vector_type(4))) float f32x4;

// fc2F[col][k] = fc_w2[k][col] * 0.25f (fp32), col in [0,2304), k in [0,16).
__global__ void prep_fc2_kernel(const float* __restrict__ fw2,
                                float* __restrict__ fc2F) {
  int tid = blockIdx.x * 256 + threadIdx.x;   // 144*256 = 36864 exactly
  int col = tid >> 4;
  int k   = tid & 15;
  fc2F[col * 16 + k] = fw2[k * 2304 + col] * 0.25f;   // fc_w2 / sqrt(HID=16)
}

__global__ __launch_bounds__(256) void tp_kernel(
    const float* __restrict__ feature,   // (20000, 80)
    const int*   __restrict__ edge,      // (2, 100000)
    const float* __restrict__ elem,      // (100000, 10)
    const float* __restrict__ esh,       // (100000, 4)
    const float* __restrict__ fw1,       // (10, 16)
    const float* __restrict__ fc2F,      // (2304, 16) fp32, pre-scaled
    float* __restrict__ out,             // (100000, 80)
    float silu_c)
{
  __shared__ __align__(16) float fc1s[160];            // fc_w1 / sqrt(10)
  __shared__ __align__(16) float s1T[4][32][20];       // [u][edge]
  __shared__ __align__(16) float v1T[4][16][3][20];    // [u][i][edge]
  __shared__ __align__(16) float dT[4][16][16];        // [u][edge] : v1.v2
  __shared__ __align__(16) float s2A[4][16];
  __shared__ __align__(16) float v2A[4][3][16];
  __shared__ __align__(16) float elemL[4][160];        // [edge*10 + j]
  __shared__ __align__(16) float hF[4][16][16];        // [edge][k] fp32
  __shared__ int dstA[4][16];
  // Weight slab shared by ALL 4 waves (identical cols every iter): 48 cols x 16 k,
  // rows padded to 20 floats (80 B): rows 0-7 tile all 32 banks, row r / r+8
  // alias 2-way (free, m136); 16B-aligned for ds_read_b128. 15360 B.
  __shared__ __align__(16) float wbufF[48 * 20];

  const int tid    = threadIdx.x;
  const int wid    = tid >> 6;
  const int l      = tid & 63;
  const int lane16 = l & 15;
  const int quad   = l >> 4;
  const int quad4  = quad * 4;

  int tile = blockIdx.x * 4 + wid;
  if (tile >= N_TILES) tile = N_TILES - 1;   // duplicate tile: identical writes
  const int eg0 = tile * 16;

  // ---- stage tiny per-tile inputs (all coalesced) ----
  if (tid < 160) fc1s[tid] = fw1[tid] / sqrtf(10.0f);
  if (l < 16) dstA[wid][l] = edge[E_TOTAL + eg0 + l];     // edge[1] row
  elemL[wid][l] = elem[eg0 * 10 + l];
  elemL[wid][64 + l] = elem[eg0 * 10 + 64 + l];
  if (l < 32) elemL[wid][128 + l] = elem[eg0 * 10 + 128 + l];
  {
    float v = esh[eg0 * 4 + l];
    int e = l >> 2, c = l & 3;
    if (c == 0) s2A[wid][e] = v;
    else        v2A[wid][c - 1][e] = v;
  }
  __syncthreads();

  // ---- feature gather: lane = channel c, loop over 16 edges ----
  {
    const int c0 = l;
    const int u0 = (c0 - 32) / 3, i0 = (c0 - 32) % 3;   // used only when c0 >= 32
    #pragma unroll 4
    for (int e = 0; e < 16; ++e) {
      int base = dstA[wid][e] * 80;
      float v = feature[base + c0];
      if (c0 < 32) s1T[wid][c0][e] = v;
      else         v1T[wid][u0][i0][e] = v;
    }
    if (l < 16) {
      const int c1 = 64 + l;
      const int u1 = (c1 - 32) / 3, i1 = (c1 - 32) % 3;
      for (int e = 0; e < 16; ++e) {
        int base = dstA[wid][e] * 80;
        v1T[wid][u1][i1][e] = feature[base + c1];
      }
    }
  }
  __syncthreads();

  // ---- h = SILU_C * silu(elem @ fc1) fp32 ; dT[u][e] = v1[u,:].v2 ----
  {
    const int e = lane16;
    #pragma unroll
    for (int q = 0; q < 4; ++q) {
      int k = quad + 4 * q;
      float a = 0.f;
      #pragma unroll
      for (int j = 0; j < 10; ++j)
        a = fmaf(elemL[wid][e * 10 + j], fc1s[j * 16 + k], a);
      hF[wid][e][k] = silu_c * a / (1.f + __expf(-a));
    }
    #pragma unroll
    for (int q = 0; q < 4; ++q) {
      int u = quad + 4 * q;
      dT[wid][u][e] = v1T[wid][u][0][e] * v2A[wid][0][e]
                    + v1T[wid][u][1][e] * v2A[wid][1][e]
                    + v1T[wid][u][2][e] * v2A[wid][2][e];
    }
  }
  __syncthreads();

  // ---- load h rows for this lane's 4 edges into registers (fp32) ----
  float hr[4][16];
  #pragma unroll
  for (int r = 0; r < 4; ++r) {
    #pragma unroll
    for (int k = 0; k < 16; ++k)
      hr[r][k] = hF[wid][quad4 + r][k];
  }

  const f32x4 zero4 = {0.f, 0.f, 0.f, 0.f};
  f32x4 as0a = zero4, as0b = zero4, at1 = zero4, as3a = zero4, as3b = zero4;
  f32x4 at2a = zero4, at2b = zero4, at2c = zero4;

  // Loop-invariant LDS read pointers: row = class*16 + lane16.
  const float* L0 = wbufF + lane16 * 20;
  const float* L1 = wbufF + (16 + lane16) * 20;
  const float* L2 = wbufF + (32 + lane16) * 20;

  // ---- Loop 1: W0 (cols u*32+[0,32)) and W1 (cols 1024+u*16+[0,16)), u in [0,32)
  // Per iter: block cooperatively stages the 48-col slab (768 dwords, 3/thread,
  // fully coalesced), then all 4 waves FMA out of LDS.
  #pragma unroll 1
  for (int u = 0; u < 32; ++u) {
    // issue global loads BEFORE the barrier: latency overlaps barrier wait
    float g0 = fc2F[u * 512 + tid];                    // cols u*32 + [0,16)
    float g1 = fc2F[u * 512 + 256 + tid];              // cols u*32 + [16,32)
    float g2 = fc2F[16384 + u * 256 + tid - 256 + 256 - (tid & 256)]; // placeholder avoided below
    g2 = fc2F[16384 + u * 256 + (tid + 512 - 512)];    // cols 1024+u*16+[0,16): d = tid+512
    g2 = fc2F[16384 + u * 256 + tid];                  // (d-512) = tid
    __syncthreads();                                   // waves done reading prev slab
    {
      int d0 = tid;          wbufF[(d0 >> 4) * 20 + (d0 & 15)] = g0;
      int d1 = tid + 256;    wbufF[(d1 >> 4) * 20 + (d1 & 15)] = g1;
      int d2 = tid + 512;    wbufF[(d2 >> 4) * 20 + (d2 & 15)] = g2;
    }
    __syncthreads();                                   // slab visible

    f32x4 d0 = zero4, d1 = zero4, d2 = zero4;
    #pragma unroll
    for (int kk = 0; kk < 4; ++kk) {
      f32x4 x0 = *(const f32x4*)(L0 + 4 * kk);
      f32x4 x1 = *(const f32x4*)(L1 + 4 * kk);
      f32x4 x2 = *(const f32x4*)(L2 + 4 * kk);
      #pragma unroll
      for (int j = 0; j < 4; ++j) {
        const int k = kk * 4 + j;
        #pragma unroll
        for (int r = 0; r < 4; ++r) {
          d0[r] = fmaf(hr[r][k], x0[j], d0[r]);
          d1[r] = fmaf(hr[r][k], x1[j], d1[r]);
          d2[r] = fmaf(hr[r][k], x2[j], d2[r]);
        }
      }
    }
    f32x4 s1v = *(const f32x4*)&s1T[wid][u][quad4];
    as0a += d0 * s1v;   // d[r] = w[edge=quad4+r][col], col = lane16 (+16)
    as0b += d1 * s1v;
    at1  += d2 * s1v;
  }

  // ---- Loop 2: W2 (cols 1536+u*16+[0,16)) and W3 (cols 1792+u*32+[0,32)), u in [0,16)
  #pragma unroll 1
  for (int u = 0; u < 16; ++u) {
    float g0 = fc2F[24576 + u * 256 + tid];            // d = tid       -> rows 0..15
    float g1 = fc2F[28672 + u * 512 + tid];            // d = tid+256   -> rows 16..31
    float g2 = fc2F[28672 + u * 512 + 256 + tid];      // d = tid+512   -> rows 32..47
    __syncthreads();
    {
      int d0 = tid;          wbufF[(d0 >> 4) * 20 + (d0 & 15)] = g0;
      int d1 = tid + 256;    wbufF[(d1 >> 4) * 20 + (d1 & 15)] = g1;
      int d2 = tid + 512;    wbufF[(d2 >> 4) * 20 + (d2 & 15)] = g2;
    }
    __syncthreads();

    f32x4 dw2 = zero4, d3a = zero4, d3b = zero4;
    #pragma unroll
    for (int kk = 0; kk < 4; ++kk) {
      f32x4 y0 = *(const f32x4*)(L0 + 4 * kk);
      f32x4 y1 = *(const f32x4*)(L1 + 4 * kk);
      f32x4 y2 = *(const f32x4*)(L2 + 4 * kk);
      #pragma unroll
      for (int j = 0; j < 4; ++j) {
        const int k = kk * 4 + j;
        #pragma unroll
        for (int r = 0; r < 4; ++r) {
          dw2[r] = fmaf(hr[r][k], y0[j], dw2[r]);
          d3a[r] = fmaf(hr[r][k], y1[j], d3a[r]);
          d3b[r] = fmaf(hr[r][k], y2[j], d3b[r]);
        }
      }
    }
    f32x4 v1v0 = *(const f32x4*)&v1T[wid][u][0][quad4];
    f32x4 v1v1 = *(const f32x4*)&v1T[wid][u][1][quad4];
    f32x4 v1v2 = *(const f32x4*)&v1T[wid][u][2][quad4];
    at2a += dw2 * v1v0;
    at2b += dw2 * v1v1;
    at2c += dw2 * v1v2;
    f32x4 dv = *(const f32x4*)&dT[wid][u][quad4];
    as3a += d3a * dv;
    as3b += d3b * dv;
  }

  // ---- epilogue: out_s = C0*s2*acc0 + C3*acc3 ; out_v = C1*v2*t1 + C2*s2*t2 ----
  f32x4 s2v = *(const f32x4*)&s2A[wid][quad4];
  f32x4 v20 = *(const f32x4*)&v2A[wid][0][quad4];
  f32x4 v21 = *(const f32x4*)&v2A[wid][1][quad4];
  f32x4 v22 = *(const f32x4*)&v2A[wid][2][quad4];
  const float CC = 0.14433756729740643f;  // 1/sqrt(48) = C0 = C1 = C2; C3 = 0.25
  #pragma unroll
  for (int r = 0; r < 4; ++r) {
    int e = eg0 + quad4 + r;
    float* op = out + (size_t)e * 80;
    op[lane16]      = CC * s2v[r] * as0a[r] + 0.25f * as3a[r];
    op[16 + lane16] = CC * s2v[r] * as0b[r] + 0.25f * as3b[r];
    float t1r = at1[r];
    float* vp = op + 32 + lane16 * 3;
    vp[0] = CC * (v20[r] * t1r + s2v[r] * at2a[r]);
    vp[1] = CC * (v21[r] * t1r + s2v[r] * at2b[r]);
    vp[2] = CC * (v22[r] * t1r + s2v[r] * at2c[r]);
  }
}

extern "C" void kernel_launch(void* const* d_in, const int* in_sizes, int n_in,
                              void* d_out, int out_size, void* d_ws, size_t ws_size,
                              hipStream_t stream) {
  const float* feature = (const float*)d_in[0];
  const int*   edge    = (const int*)d_in[1];
  const float* elem    = (const float*)d_in[2];
  const float* esh     = (const float*)d_in[3];
  const float* fw1     = (const float*)d_in[4];
  const float* fw2     = (const float*)d_in[5];
  float* out = (float*)d_out;
  float* fc2F = (float*)d_ws;   // 2304*16*4 B = 147456 B

  // SILU_C: replicate np.trapz(silu(x)^2 * N(0,1) pdf, 200001 pts on [-12,12])
  const int NPTS = 200001;
  const double dx = 24.0 / 200000.0;
  const double inv_sqrt2pi = 0.3989422804014326779;
  double sum = 0.0;
  double x0 = -12.0;
  double s0 = x0 / (1.0 + exp(-x0));
  double y0 = s0 * s0 * exp(-0.5 * x0 * x0) * inv_sqrt2pi;
  for (int i = 1; i < NPTS; ++i) {
    double x1 = -12.0 + i * dx;
    double s1 = x1 / (1.0 + exp(-x1));
    double y1 = s1 * s1 * exp(-0.5 * x1 * x1) * inv_sqrt2pi;
    sum += 0.5 * (y0 + y1) * dx;
    y0 = y1;
  }
  float silu_c = (float)(1.0 / sqrt(sum));

  hipLaunchKernelGGL(prep_fc2_kernel, dim3(144), dim3(256), 0, stream, fw2, fc2F);
  hipLaunchKernelGGL(tp_kernel, dim3(1563), dim3(256), 0, stream,
                     feature, edge, elem, esh, fw1, fc2F, out, silu_c);
}

// Round 7
// 199.302 us; speedup vs baseline: 1.8098x; 1.0346x over previous
//
#include <hip/hip_runtime.h>
#include <math.h>

#define E_TOTAL 100000
#define N_TILES 6250   // E_TOTAL / 16

typedef __attribute__((ext_vector_type(4))) float f32x4;

// fc2F[col][k] = fc_w2[k][col] * 0.25f (fp32), col in [0,2304), k in [0,16).
__global__ void prep_fc2_kernel(const float* __restrict__ fw2,
                                float* __restrict__ fc2F) {
  int tid = blockIdx.x * 256 + threadIdx.x;   // 144*256 = 36864 exactly
  int col = tid >> 4;
  int k   = tid & 15;
  fc2F[col * 16 + k] = fw2[k * 2304 + col] * 0.25f;   // fc_w2 / sqrt(HID=16)
}

__global__ __launch_bounds__(256) void tp_kernel(
    const float* __restrict__ feature,   // (20000, 80)
    const int*   __restrict__ edge,      // (2, 100000)
    const float* __restrict__ elem,      // (100000, 10)
    const float* __restrict__ esh,       // (100000, 4)
    const float* __restrict__ fw1,       // (10, 16)
    const float* __restrict__ fc2F,      // (2304, 16) fp32, pre-scaled
    float* __restrict__ out,             // (100000, 80)
    float silu_c)
{
  __shared__ __align__(16) float fc1s[160];            // fc_w1 / sqrt(10)
  __shared__ __align__(16) float s1T[4][32][20];       // [u][edge]
  __shared__ __align__(16) float v1T[4][16][3][20];    // [u][i][edge]
  __shared__ __align__(16) float dT[4][16][16];        // [u][edge] : v1.v2
  __shared__ __align__(16) float s2A[4][16];
  __shared__ __align__(16) float v2A[4][3][16];
  __shared__ __align__(16) float elemL[4][160];        // [edge*10 + j]
  __shared__ __align__(16) float hF[4][16][16];        // [edge][k] fp32
  __shared__ int dstA[4][16];
  // DOUBLE-BUFFERED weight slab (48 cols x 16 k, rows padded to 20 floats:
  // 16-lane b128 reads land on all 32 banks exactly 2-way = free, m136).
  // 2 x 3840 B; prefetch slab(u+1) during compute(u) hides the L2 latency
  // that was serial in R6. Single barrier/iter is safe: buf[nxt] was last
  // READ in iter u-1 before that iter's barrier.
  __shared__ __align__(16) float wbufF[2][48 * 20];

  const int tid    = threadIdx.x;
  const int wid    = tid >> 6;
  const int l      = tid & 63;
  const int lane16 = l & 15;
  const int quad   = l >> 4;
  const int quad4  = quad * 4;

  int tile = blockIdx.x * 4 + wid;
  if (tile >= N_TILES) tile = N_TILES - 1;   // duplicate tile: identical writes
  const int eg0 = tile * 16;

  // ---- stage tiny per-tile inputs (all coalesced) ----
  if (tid < 160) fc1s[tid] = fw1[tid] / sqrtf(10.0f);
  if (l < 16) dstA[wid][l] = edge[E_TOTAL + eg0 + l];     // edge[1] row
  elemL[wid][l] = elem[eg0 * 10 + l];
  elemL[wid][64 + l] = elem[eg0 * 10 + 64 + l];
  if (l < 32) elemL[wid][128 + l] = elem[eg0 * 10 + 128 + l];
  {
    float v = esh[eg0 * 4 + l];
    int e = l >> 2, c = l & 3;
    if (c == 0) s2A[wid][e] = v;
    else        v2A[wid][c - 1][e] = v;
  }
  __syncthreads();

  // ---- feature gather: lane = channel c, loop over 16 edges ----
  {
    const int c0 = l;
    const int u0 = (c0 - 32) / 3, i0 = (c0 - 32) % 3;   // used only when c0 >= 32
    #pragma unroll 4
    for (int e = 0; e < 16; ++e) {
      int base = dstA[wid][e] * 80;
      float v = feature[base + c0];
      if (c0 < 32) s1T[wid][c0][e] = v;
      else         v1T[wid][u0][i0][e] = v;
    }
    if (l < 16) {
      const int c1 = 64 + l;
      const int u1 = (c1 - 32) / 3, i1 = (c1 - 32) % 3;
      for (int e = 0; e < 16; ++e) {
        int base = dstA[wid][e] * 80;
        v1T[wid][u1][i1][e] = feature[base + c1];
      }
    }
  }
  __syncthreads();

  // ---- h = SILU_C * silu(elem @ fc1) fp32 ; dT[u][e] = v1[u,:].v2 ----
  {
    const int e = lane16;
    #pragma unroll
    for (int q = 0; q < 4; ++q) {
      int k = quad + 4 * q;
      float a = 0.f;
      #pragma unroll
      for (int j = 0; j < 10; ++j)
        a = fmaf(elemL[wid][e * 10 + j], fc1s[j * 16 + k], a);
      hF[wid][e][k] = silu_c * a / (1.f + __expf(-a));
    }
    #pragma unroll
    for (int q = 0; q < 4; ++q) {
      int u = quad + 4 * q;
      dT[wid][u][e] = v1T[wid][u][0][e] * v2A[wid][0][e]
                    + v1T[wid][u][1][e] * v2A[wid][1][e]
                    + v1T[wid][u][2][e] * v2A[wid][2][e];
    }
  }
  __syncthreads();

  // ---- load h rows for this lane's 4 edges into registers (fp32) ----
  float hr[4][16];
  #pragma unroll
  for (int r = 0; r < 4; ++r) {
    #pragma unroll
    for (int k = 0; k < 16; ++k)
      hr[r][k] = hF[wid][quad4 + r][k];
  }

  const f32x4 zero4 = {0.f, 0.f, 0.f, 0.f};
  f32x4 as0a = zero4, as0b = zero4, at1 = zero4, as3a = zero4, as3b = zero4;
  f32x4 at2a = zero4, at2b = zero4, at2c = zero4;

  // Slab u in [0,48): u<32 -> {W0 lo16, W0 hi16, W1}; u>=32 (v=u-32) -> {W2, W3 lo16, W3 hi16}
  // Global addresses for this thread's 3 staged dwords:
  //   d0 = tid (rows 0-15), d1 = tid+256 (rows 16-31), d2 = tid+512 (rows 32-47)
  const int wrow0 = (tid >> 4) * 20 + (tid & 15);          // row tid>>4
  const int wrow1 = (16 + (tid >> 4)) * 20 + (tid & 15);
  const int wrow2 = (32 + (tid >> 4)) * 20 + (tid & 15);

  // ---- prologue: stage slab 0 into buf 0 ----
  {
    float g0 = fc2F[tid];            // u=0: cols [0,16)
    float g1 = fc2F[256 + tid];      //      cols [16,32)
    float g2 = fc2F[16384 + tid];    //      cols 1024+[0,16)
    wbufF[0][wrow0] = g0;
    wbufF[0][wrow1] = g1;
    wbufF[0][wrow2] = g2;
  }
  __syncthreads();

  // ---- Loop 1: u in [0,32): compute W0/W1 from buf[u&1], prefetch slab u+1 ----
  #pragma unroll 1
  for (int u = 0; u < 32; ++u) {
    // prefetch slab u+1 (issue now; latency hides under compute below)
    float g0, g1, g2;
    {
      int un = u + 1;
      if (un < 32) {
        g0 = fc2F[un * 512 + tid];
        g1 = fc2F[un * 512 + 256 + tid];
        g2 = fc2F[16384 + un * 256 + tid];
      } else {            // first slab of loop 2 (v = 0)
        g0 = fc2F[24576 + tid];
        g1 = fc2F[28672 + tid];
        g2 = fc2F[28672 + 256 + tid];
      }
    }

    const float* L0 = &wbufF[u & 1][lane16 * 20];
    const float* L1 = L0 + 16 * 20;
    const float* L2 = L0 + 32 * 20;
    f32x4 d0 = zero4, d1 = zero4, d2 = zero4;
    #pragma unroll
    for (int kk = 0; kk < 4; ++kk) {
      f32x4 x0 = *(const f32x4*)(L0 + 4 * kk);
      f32x4 x1 = *(const f32x4*)(L1 + 4 * kk);
      f32x4 x2 = *(const f32x4*)(L2 + 4 * kk);
      #pragma unroll
      for (int j = 0; j < 4; ++j) {
        const int k = kk * 4 + j;
        #pragma unroll
        for (int r = 0; r < 4; ++r) {
          d0[r] = fmaf(hr[r][k], x0[j], d0[r]);
          d1[r] = fmaf(hr[r][k], x1[j], d1[r]);
          d2[r] = fmaf(hr[r][k], x2[j], d2[r]);
        }
      }
    }
    f32x4 s1v = *(const f32x4*)&s1T[wid][u][quad4];
    as0a += d0 * s1v;   // d[r] = w[edge=quad4+r][col], col = lane16 (+16)
    as0b += d1 * s1v;
    at1  += d2 * s1v;

    // write prefetched slab into the other buffer; single barrier publishes it
    float* W = wbufF[(u + 1) & 1];
    W[wrow0] = g0;
    W[wrow1] = g1;
    W[wrow2] = g2;
    __syncthreads();
  }

  // ---- Loop 2: v in [0,16): compute W2/W3 from buf[(32+v)&1], prefetch v+1 ----
  #pragma unroll 1
  for (int v = 0; v < 16; ++v) {
    float g0 = 0.f, g1 = 0.f, g2 = 0.f;
    if (v < 15) {
      int vn = v + 1;
      g0 = fc2F[24576 + vn * 256 + tid];
      g1 = fc2F[28672 + vn * 512 + tid];
      g2 = fc2F[28672 + vn * 512 + 256 + tid];
    }

    const float* L0 = &wbufF[v & 1][lane16 * 20];   // (32+v)&1 == v&1
    const float* L1 = L0 + 16 * 20;
    const float* L2 = L0 + 32 * 20;
    f32x4 dw2 = zero4, d3a = zero4, d3b = zero4;
    #pragma unroll
    for (int kk = 0; kk < 4; ++kk) {
      f32x4 y0 = *(const f32x4*)(L0 + 4 * kk);
      f32x4 y1 = *(const f32x4*)(L1 + 4 * kk);
      f32x4 y2 = *(const f32x4*)(L2 + 4 * kk);
      #pragma unroll
      for (int j = 0; j < 4; ++j) {
        const int k = kk * 4 + j;
        #pragma unroll
        for (int r = 0; r < 4; ++r) {
          dw2[r] = fmaf(hr[r][k], y0[j], dw2[r]);
          d3a[r] = fmaf(hr[r][k], y1[j], d3a[r]);
          d3b[r] = fmaf(hr[r][k], y2[j], d3b[r]);
        }
      }
    }
    f32x4 v1v0 = *(const f32x4*)&v1T[wid][v][0][quad4];
    f32x4 v1v1 = *(const f32x4*)&v1T[wid][v][1][quad4];
    f32x4 v1v2 = *(const f32x4*)&v1T[wid][v][2][quad4];
    at2a += dw2 * v1v0;
    at2b += dw2 * v1v1;
    at2c += dw2 * v1v2;
    f32x4 dv = *(const f32x4*)&dT[wid][v][quad4];
    as3a += d3a * dv;
    as3b += d3b * dv;

    if (v < 15) {
      float* W = wbufF[(v + 1) & 1];
      W[wrow0] = g0;
      W[wrow1] = g1;
      W[wrow2] = g2;
      __syncthreads();
    }
  }

  // ---- epilogue: out_s = C0*s2*acc0 + C3*acc3 ; out_v = C1*v2*t1 + C2*s2*t2 ----
  f32x4 s2v = *(const f32x4*)&s2A[wid][quad4];
  f32x4 v20 = *(const f32x4*)&v2A[wid][0][quad4];
  f32x4 v21 = *(const f32x4*)&v2A[wid][1][quad4];
  f32x4 v22 = *(const f32x4*)&v2A[wid][2][quad4];
  const float CC = 0.14433756729740643f;  // 1/sqrt(48) = C0 = C1 = C2; C3 = 0.25
  #pragma unroll
  for (int r = 0; r < 4; ++r) {
    int e = eg0 + quad4 + r;
    float* op = out + (size_t)e * 80;
    op[lane16]      = CC * s2v[r] * as0a[r] + 0.25f * as3a[r];
    op[16 + lane16] = CC * s2v[r] * as0b[r] + 0.25f * as3b[r];
    float t1r = at1[r];
    float* vp = op + 32 + lane16 * 3;
    vp[0] = CC * (v20[r] * t1r + s2v[r] * at2a[r]);
    vp[1] = CC * (v21[r] * t1r + s2v[r] * at2b[r]);
    vp[2] = CC * (v22[r] * t1r + s2v[r] * at2c[r]);
  }
}

extern "C" void kernel_launch(void* const* d_in, const int* in_sizes, int n_in,
                              void* d_out, int out_size, void* d_ws, size_t ws_size,
                              hipStream_t stream) {
  const float* feature = (const float*)d_in[0];
  const int*   edge    = (const int*)d_in[1];
  const float* elem    = (const float*)d_in[2];
  const float* esh     = (const float*)d_in[3];
  const float* fw1     = (const float*)d_in[4];
  const float* fw2     = (const float*)d_in[5];
  float* out = (float*)d_out;
  float* fc2F = (float*)d_ws;   // 2304*16*4 B = 147456 B

  // SILU_C: replicate np.trapz(silu(x)^2 * N(0,1) pdf, 200001 pts on [-12,12])
  const int NPTS = 200001;
  const double dx = 24.0 / 200000.0;
  const double inv_sqrt2pi = 0.3989422804014326779;
  double sum = 0.0;
  double x0 = -12.0;
  double s0 = x0 / (1.0 + exp(-x0));
  double y0 = s0 * s0 * exp(-0.5 * x0 * x0) * inv_sqrt2pi;
  for (int i = 1; i < NPTS; ++i) {
    double x1 = -12.0 + i * dx;
    double s1 = x1 / (1.0 + exp(-x1));
    double y1 = s1 * s1 * exp(-0.5 * x1 * x1) * inv_sqrt2pi;
    sum += 0.5 * (y0 + y1) * dx;
    y0 = y1;
  }
  float silu_c = (float)(1.0 / sqrt(sum));

  hipLaunchKernelGGL(prep_fc2_kernel, dim3(144), dim3(256), 0, stream, fw2, fc2F);
  hipLaunchKernelGGL(tp_kernel, dim3(1563), dim3(256), 0, stream,
                     feature, edge, elem, esh, fw1, fc2F, out, silu_c);
}